// Round 8
// baseline (271.714 us; speedup 1.0000x reference)
//
#include <hip/hip_runtime.h>
#include <hip/hip_bf16.h>

#define NB 8192   // batch
#define ND 1024   // feature dim

typedef __bf16 bf16x8 __attribute__((ext_vector_type(8)));
typedef float  f32x4  __attribute__((ext_vector_type(4)));

// async global -> LDS, 16B per lane. LDS dest = wave-uniform base + lane*16.
__device__ inline void gload_lds16(const void* g, void* l) {
    __builtin_amdgcn_global_load_lds(
        (const __attribute__((address_space(1))) unsigned int*)g,
        (__attribute__((address_space(3))) unsigned int*)l,
        16, 0, 0);
}

__device__ inline unsigned short f2bf(float x) {
    unsigned int u = __float_as_uint(x);
    return (unsigned short)((u + 0x7fffu + ((u >> 16) & 1u)) >> 16);
}

#define BARRIER() asm volatile("s_barrier" ::: "memory")
#define VMCNT4()  asm volatile("s_waitcnt vmcnt(4)" ::: "memory")
#define VMCNT0()  asm volatile("s_waitcnt vmcnt(0)" ::: "memory")

// ---------------------------------------------------------------------------
// Kernel 1: per-row L2 norms of A and B + bf16 conversion into workspace.
// ---------------------------------------------------------------------------
__global__ __launch_bounds__(256) void prep_kernel(
    const float* __restrict__ A, const float* __restrict__ Bm,
    unsigned short* __restrict__ wa, unsigned short* __restrict__ wb,
    float* __restrict__ na, float* __restrict__ nb)
{
    int b = blockIdx.x;
    int wid = threadIdx.x >> 6, lane = threadIdx.x & 63;
    const float* src; unsigned short* dst; float* nrm; int row;
    if (b < 2048) { src = A;  dst = wa; nrm = na; row = b * 4 + wid; }
    else          { src = Bm; dst = wb; nrm = nb; row = (b - 2048) * 4 + wid; }

    const float*    rp = src + (size_t)row * ND;
    unsigned short* wp = dst + (size_t)row * ND;

    float ss = 0.f;
#pragma unroll
    for (int t = 0; t < 4; ++t) {
        int c = lane * 4 + t * 256;
        float4 v = *reinterpret_cast<const float4*>(rp + c);
        ss += v.x * v.x + v.y * v.y + v.z * v.z + v.w * v.w;
        ushort4 u;
        u.x = f2bf(v.x); u.y = f2bf(v.y); u.z = f2bf(v.z); u.w = f2bf(v.w);
        *reinterpret_cast<ushort4*>(wp + c) = u;
    }
#pragma unroll
    for (int off = 32; off; off >>= 1) ss += __shfl_xor(ss, off);
    if (lane == 0) nrm[row] = sqrtf(ss);
}

// ---------------------------------------------------------------------------
// Kernel 2: label histogram (integer LDS atomics -> deterministic).
// ---------------------------------------------------------------------------
__global__ __launch_bounds__(256) void hist_kernel(
    const int* __restrict__ labels, int* __restrict__ hist)
{
    __shared__ int h[128];
    int tid = threadIdx.x;
    if (tid < 128) h[tid] = 0;
    __syncthreads();
    for (int i = tid; i < NB; i += 256) atomicAdd(&h[labels[i]], 1);
    __syncthreads();
    if (tid < 128) hist[tid] = h[tid];
}

// ---------------------------------------------------------------------------
// Kernel 3: 128x128-tile bf16 GEMM (m97 structure), BK=32, TRI-buffered LDS
// (3 x 16 KiB = 48 KiB) -> ~3 blocks/CU co-resident (VGPR-bound), m114
// inter-block overlap hides barriers/epilogue. Depth-2 prefetch: at iter t
// stage tile t+2, compute tile t, then vmcnt(4) = wait only tile t+1 (its
// loads issued a full compute phase ago -> ~0 stall; never drains the
// just-issued loads). Raw s_barrier (no implicit full drain). T2 granule
// swizzle kills R1's 1.7e7 bank conflicts. XCD-row mapping for L2 reuse.
// Epilogue: scale to cos, write C, fused per-row loss partials.
// ---------------------------------------------------------------------------
__global__ __launch_bounds__(256) void gemm_cos(
    const unsigned short* __restrict__ wa, const unsigned short* __restrict__ wb,
    const float* __restrict__ na, const float* __restrict__ nb,
    const int* __restrict__ labels,
    float* __restrict__ C, float* __restrict__ pe, float* __restrict__ pm)
{
    // 3 bufs x [A 128x32 | B 128x32] bf16 = 3 x 8192 shorts = 48 KiB
    __shared__ unsigned short lds[24576];

    const int bid = blockIdx.x;                 // 4096 blocks
    const int tm  = (bid & 7) * 8 + ((bid >> 3) & 7);   // XCD owns 8 tm rows
    const int tn  = bid >> 6;                            // B streams

    const int tid  = threadIdx.x;
    const int lane = tid & 63;
    const int wid  = tid >> 6;
    const int wr   = wid >> 1, wc = wid & 1;
    const int l15  = lane & 15, lg = lane >> 4;

    const int m0 = tm * 128, n0 = tn * 128;

    // Staging: thread -> row tid>>2 (0..63 per call), granule tid&3; global
    // granule pre-swizzled: (tid&3) ^ ((row>>1)&3), row = tid>>2.
    const int srow = tid >> 2;
    const int sg   = (tid & 3) ^ ((tid >> 3) & 3);
    const unsigned short* pA0 = wa + (size_t)(m0 + srow) * ND + sg * 8;
    const unsigned short* pA1 = pA0 + 64 * ND;
    const unsigned short* pB0 = wb + (size_t)(n0 + srow) * ND + sg * 8;
    const unsigned short* pB1 = pB0 + 64 * ND;
    const int stW = wid * 512;   // wave-uniform LDS dest base per 64-row chunk

    // Fragment reads: kg = (lg ^ ((row>>1)&3))*8; row bits from l15 only.
    const int kg  = (lg ^ ((lane >> 1) & 3)) * 8;
    const int rdA = wr * 2048 + l15 * 32 + kg;            // + m*512
    const int rdB = 4096 + wc * 2048 + l15 * 32 + kg;     // + n*512

    f32x4 acc[4][4];
#pragma unroll
    for (int i = 0; i < 4; ++i)
#pragma unroll
        for (int j = 0; j < 4; ++j) acc[i][j] = (f32x4){0.f, 0.f, 0.f, 0.f};

#define STAGE(t, BUF) do { \
    gload_lds16(pA0 + (t) * 32, &lds[(BUF) + stW]); \
    gload_lds16(pA1 + (t) * 32, &lds[(BUF) + 2048 + stW]); \
    gload_lds16(pB0 + (t) * 32, &lds[(BUF) + 4096 + stW]); \
    gload_lds16(pB1 + (t) * 32, &lds[(BUF) + 6144 + stW]); } while (0)

#define COMPUTE(BUF) do { \
    bf16x8 bq[4], af[4]; \
    _Pragma("unroll") \
    for (int n_ = 0; n_ < 4; ++n_) \
        bq[n_] = *reinterpret_cast<const bf16x8*>(&lds[(BUF) + rdB + n_ * 512]); \
    _Pragma("unroll") \
    for (int m_ = 0; m_ < 4; ++m_) \
        af[m_] = *reinterpret_cast<const bf16x8*>(&lds[(BUF) + rdA + m_ * 512]); \
    _Pragma("unroll") \
    for (int m_ = 0; m_ < 4; ++m_) \
        _Pragma("unroll") \
        for (int n_ = 0; n_ < 4; ++n_) \
            acc[m_][n_] = __builtin_amdgcn_mfma_f32_16x16x32_bf16( \
                af[m_], bq[n_], acc[m_][n_], 0, 0, 0); \
    } while (0)

    // Prologue: tiles 0,1 staged (8 loads/wave); wait tile 0 only.
    STAGE(0, 0);
    STAGE(1, 8192);
    VMCNT4();
    BARRIER();

#pragma unroll
    for (int t = 0; t < 32; ++t) {
        const int cb  = (t % 3) * 8192;
        const int nb2 = ((t + 2) % 3) * 8192;
        if (t < 30) STAGE(t + 2, nb2);        // issue-early (depth 2)
        COMPUTE(cb);                          // ~1000+ cyc of load flight
        if (t < 29)      VMCNT4();            // wait-late: only tile t+1
        else if (t < 31) VMCNT0();            // drain tail tiles
        BARRIER();
    }

#undef COMPUTE
#undef STAGE

    // ---------------- epilogue: cos write + fused loss partials ------------
    __syncthreads();                 // LDS reusable
    float* pl = reinterpret_cast<float*>(lds);   // [128 rows][2 wc][2] floats

    float nbv[4]; int labc[4];
#pragma unroll
    for (int n = 0; n < 4; ++n) {
        int c = n0 + wc * 64 + n * 16 + l15;
        nbv[n] = nb[c]; labc[n] = labels[c];
    }

#pragma unroll
    for (int m = 0; m < 4; ++m) {
#pragma unroll
        for (int jj = 0; jj < 4; ++jj) {
            int rl = wr * 64 + m * 16 + lg * 4 + jj;   // 0..127
            int r  = m0 + rl;
            float nav = na[r]; int labr = labels[r];
            float es = 0.f, ms = 0.f;
#pragma unroll
            for (int n = 0; n < 4; ++n) {
                int c = n0 + wc * 64 + n * 16 + l15;
                float v = acc[m][n][jj] / fmaxf(nav * nbv[n], 1e-8f);
                C[(size_t)r * NB + c] = v;
                es += __expf(v);
                ms += (labc[n] == labr) ? v : 0.f;
            }
#pragma unroll
            for (int off = 1; off < 16; off <<= 1) {
                es += __shfl_xor(es, off);
                ms += __shfl_xor(ms, off);
            }
            if (l15 == 0) {
                int o = rl * 4 + wc * 2;
                pl[o] = es; pl[o + 1] = ms;
            }
        }
    }
    __syncthreads();
    if (tid < 128) {
        float es = pl[tid * 4]     + pl[tid * 4 + 2];
        float ms = pl[tid * 4 + 1] + pl[tid * 4 + 3];
        pe[tn * NB + m0 + tid] = es;
        pm[tn * NB + m0 + tid] = ms;
    }
}

// ---------------------------------------------------------------------------
// Kernel 4: reduce 64 column-tile partials -> per-row loss.
// ---------------------------------------------------------------------------
__global__ __launch_bounds__(256) void loss_final(
    const float* __restrict__ pe, const float* __restrict__ pm,
    const int* __restrict__ labels, const int* __restrict__ hist,
    float* __restrict__ per_row)
{
    int row = blockIdx.x * 256 + threadIdx.x;
    float es = 0.f, ms = 0.f;
#pragma unroll
    for (int t = 0; t < 64; ++t) {
        es += pe[t * NB + row];
        ms += pm[t * NB + row];
    }
    per_row[row] = logf(es) - ms / (float)hist[labels[row]];
}

// ---------------------------------------------------------------------------
// Kernel 5: deterministic mean of per_row -> out[0]
// ---------------------------------------------------------------------------
__global__ __launch_bounds__(256) void finalize(
    const float* __restrict__ per_row, float* __restrict__ out)
{
    __shared__ float sm[256];
    float s = 0.f;
    for (int i = threadIdx.x; i < NB; i += 256) s += per_row[i];
    sm[threadIdx.x] = s;
    __syncthreads();
    for (int k = 128; k; k >>= 1) {
        if (threadIdx.x < k) sm[threadIdx.x] += sm[threadIdx.x + k];
        __syncthreads();
    }
    if (threadIdx.x == 0) out[0] = sm[0] * (1.0f / (float)NB);
}

extern "C" void kernel_launch(void* const* d_in, const int* in_sizes, int n_in,
                              void* d_out, int out_size, void* d_ws, size_t ws_size,
                              hipStream_t stream) {
    const int*   labels = (const int*)d_in[0];
    const float* A      = (const float*)d_in[1];
    const float* Bm     = (const float*)d_in[2];
    float* out = (float*)d_out;

    // workspace layout (~38.2 MB)
    char* ws = (char*)d_ws;
    unsigned short* wa = (unsigned short*)(ws);                     // 16 MB
    unsigned short* wb = (unsigned short*)(ws + 16777216);          // 16 MB
    float* na      = (float*)(ws + 33554432);                       // 32 KB
    float* nb      = (float*)(ws + 33554432 + 32768);               // 32 KB
    float* per_row = (float*)(ws + 33554432 + 65536);               // 32 KB
    int*   hist    = (int*)  (ws + 33554432 + 98304);               // 512 B
    float* pe      = (float*)(ws + 33554432 + 131072);              // 2 MB
    float* pm      = (float*)(ws + 33554432 + 131072 + 2097152);    // 2 MB

    float* cosm = out + 1;   // out[0]=loss, out[1..] = cos_score row-major

    prep_kernel<<<4096, 256, 0, stream>>>(A, Bm, wa, wb, na, nb);
    hist_kernel<<<1,    256, 0, stream>>>(labels, hist);
    gemm_cos   <<<4096, 256, 0, stream>>>(wa, wb, na, nb, labels, cosm, pe, pm);
    loss_final <<<32,   256, 0, stream>>>(pe, pm, labels, hist, per_row);
    finalize   <<<1,    256, 0, stream>>>(per_row, out);
}